// Round 2
// baseline (255.273 us; speedup 1.0000x reference)
//
#include <hip/hip_runtime.h>

// out = x @ H, H = 4096x4096 Sylvester Hadamard (+/-1). H[i][j] =
// (-1)^popcount(i&j) is symmetric -> each output row is the Walsh-Hadamard
// transform of the input row: O(N log N) butterflies instead of a 275-GFLOP
// fp32 matmul. Memory-bound: 268 MB total traffic, HBM floor ~43 us at
// 6.3 TB/s. H (d_in[1]) is never read.
//
// R4 vs R3: rocprof showed the kernel is NOT in the top-5 dispatches (all
// fillBuffer @ ~79 us) -> kernel itself < 79 us; dur_us=252.9 is dominated
// by the harness poison fills (~180 us fixed). Attack the kernel's gap to
// the HBM floor: R3 did 3 LDS passes (256 scalar + 32 b128 wave-insts/row,
// ~1870 LDS cyc + heavy per-address VALU + 3 barriers). R4: 64 threads/
// block, 64 floats/thread, ONE LDS transpose:
//   phase A: 16x b128 loads (thread-contiguous), butterfly bits 0-5 in regs
//   LDS:     16x b128 swizzled writes | barrier | 64x b32 swizzled reads
//   phase B: butterfly bits 6-11 in regs, 64x coalesced scalar stores
// Per-row LDS 1870 -> 563 cyc, addressing ~folds into imm offsets,
// barriers 3 -> 1. Predicted kernel ~45-55 us (HBM-bound).

constexpr int N = 4096;
constexpr int ROWS = 8192;

typedef float f32x4 __attribute__((ext_vector_type(4)));

__global__ __launch_bounds__(64) void fwht4096_kernel(const float* __restrict__ x,
                                                      float* __restrict__ out) {
    // LDS layout: element e stored at word address A(e) = e ^ (((e>>6)&7)<<2)
    // (XOR low 3 bits of e[11:6] into e[4:2]).
    //  - phase-A b128 writes (fixed q): 8 lanes per 4-bank group, uniformly
    //    balanced -> optimal for a 256-word wave access.
    //  - phase-B b32 reads (fixed m2): lanes hit (t ^ C)&31 -> 2 lanes/bank,
    //    free on gfx950.
    __shared__ __align__(16) float lds[N];
    const int t = threadIdx.x;  // 0..63, one wave per block
    const size_t rowoff = (size_t)blockIdx.x * N;
    const float* __restrict__ xr = x + rowoff;
    float* __restrict__ yr = out + rowoff;

    float v[64];

    // ---- Phase A: thread t owns e = (t<<6) | m, m = 0..63 (bits 0-5 local).
    // Loads: 16 x float4, thread-contiguous 256 B (one base VGPR pair +
    // 13-bit imm offsets). Wave-inst touches 64 lines x 16 B; the 4x per-line
    // re-touch is absorbed by L1/L2, HBM fetches each line once.
#pragma unroll
    for (int q = 0; q < 16; ++q) {
        const f32x4 d = *reinterpret_cast<const f32x4*>(xr + (t << 6) + 4 * q);
        v[4 * q + 0] = d[0];
        v[4 * q + 1] = d[1];
        v[4 * q + 2] = d[2];
        v[4 * q + 3] = d[3];
    }
    // Butterfly bits 0-5 (h = 1,2,4,8,16,32). All indices compile-time
    // (full unroll) -> stays in registers (no scratch).
#pragma unroll
    for (int b = 1; b < 64; b <<= 1) {
#pragma unroll
        for (int m = 0; m < 64; ++m) {
            if ((m & b) == 0) {
                const float a = v[m], c = v[m | b];
                v[m]     = a + c;
                v[m | b] = a - c;
            }
        }
    }

    // ---- LDS write: quad (m = 4q..4q+3) of element (t<<6)|m at word
    // address (t<<6) | ((4q) ^ T), T = (t&7)<<2. Quad alignment preserved
    // (XOR only touches bits 2-4).
    {
        const int T = (t & 7) << 2;
        const int wbase = t << 6;
#pragma unroll
        for (int q = 0; q < 16; ++q) {
            f32x4 d;
            d[0] = v[4 * q + 0];
            d[1] = v[4 * q + 1];
            d[2] = v[4 * q + 2];
            d[3] = v[4 * q + 3];
            *reinterpret_cast<f32x4*>(&lds[wbase | ((4 * q) ^ T)]) = d;
        }
    }
    __syncthreads();  // single-wave block: compiles to waitcnt + cheap barrier

    // ---- LDS read: thread t now owns e = (m2<<6) | t, m2 = 0..63
    // (bits 6-11 local). Address (m2<<6) | (t ^ ((m2&7)<<2)): 8 distinct
    // address VGPRs (CSE'd xors) + 16-bit imm offsets m2<<8.
#pragma unroll
    for (int m2 = 0; m2 < 64; ++m2) {
        v[m2] = lds[(m2 << 6) | (t ^ ((m2 & 7) << 2))];
    }

    // ---- Phase B: butterfly bits 6-11 (h = 64,...,2048) on local index m2.
#pragma unroll
    for (int b = 1; b < 64; b <<= 1) {
#pragma unroll
        for (int m = 0; m < 64; ++m) {
            if ((m & b) == 0) {
                const float a = v[m], c = v[m | b];
                v[m]     = a + c;
                v[m | b] = a - c;
            }
        }
    }

    // ---- Store: out[(m2<<6) | t] — each wave-inst writes a contiguous
    // 256 B (4 full 64-B lines) -> perfectly coalesced; nontemporal is safe
    // at full-line coverage and keeps 134 MB of output out of L2/L3.
#pragma unroll
    for (int m2 = 0; m2 < 64; ++m2) {
        __builtin_nontemporal_store(v[m2], yr + (m2 << 6) + t);
    }
}

extern "C" void kernel_launch(void* const* d_in, const int* in_sizes, int n_in,
                              void* d_out, int out_size, void* d_ws, size_t ws_size,
                              hipStream_t stream) {
    (void)n_in; (void)d_ws; (void)ws_size; (void)out_size; (void)in_sizes;
    const float* x = (const float*)d_in[0];  // [8192, 4096] fp32
    float* out = (float*)d_out;              // [8192, 4096] fp32
    // Fixed problem shape: N_TOKENS = 8192 (R3 confirmed in_sizes[0]/N was
    // already 8192; keep it hardcoded and unit-unambiguous).
    fwht4096_kernel<<<ROWS, 64, 0, stream>>>(x, out);
}

// Round 5
// 255.117 us; speedup vs baseline: 1.0006x; 1.0006x over previous
//
#include <hip/hip_runtime.h>

// out = x @ H, H = 4096x4096 Sylvester Hadamard (+/-1). H[i][j] =
// (-1)^popcount(i&j) is symmetric -> each output row is the Walsh-Hadamard
// transform of the input row: O(N log N) butterflies instead of a 275-GFLOP
// fp32 matmul. H (d_in[1]) is never read. Traffic floor: 134 MB in (~half
// L3-resident per rocprof) + 134 MB out -> ~32-43 us.
//
// R7 vs R5/R6: R5 and R6 (identical source, with __builtin_amdgcn_mov_dpp
// butterflies) both died with "container failed twice" — possibly a
// kernel-triggered toolchain/capture hang. This round swaps the ONLY exotic
// ingredient: DPP quad-perm -> __shfl_xor (ds_swizzle path, well-trodden).
// Everything else is byte-identical to R5. Theory under test is unchanged:
// R4 was LATENCY-bound (kernel 84 us, hbm 2.4 TB/s = 30%, VALUBusy 12%,
// Occupancy 18%, conflicts 0): 64-thr blocks w/ 16 KB LDS -> 10 waves/CU.
// LDS/row is irreducible (transpose needs the whole row), so raise waves
// per allocation: 128 thr/row -> 20 waves/CU. Thread owns 32 elems,
// bit split 5+2+5:
//   phase A: bits 0-4 in regs; bits 5-6 (= lane&3) via __shfl_xor(1/2)
//            butterflies (+ per-lane sign fma)
//   LDS:     8x b128 swizzled writes | barrier | 32x b32 reads (2-way = free)
//   phase B: bits 7-11 in regs; 32 contiguous-256B nontemporal stores.

constexpr int N = 4096;
constexpr int ROWS = 8192;

typedef float f32x4 __attribute__((ext_vector_type(4)));

__global__ __launch_bounds__(128) void fwht4096_kernel(const float* __restrict__ x,
                                                       float* __restrict__ out) {
    // LDS layout: element e at word address A(e) = e ^ (((e>>5)&7)<<2).
    //  - phase-A b128 writes (fixed q): bank group 4*(q ^ (t&7)) -> the 8
    //    lane-classes cover all 8 groups uniformly -> structurally minimal
    //    (8 words/bank per wave-inst, fully balanced).
    //  - phase-B b32 reads (fixed m2): bank = (l&31) ^ c, upper/lower lane
    //    halves differ in bit 2 -> exactly 2 lanes/bank, free on gfx950.
    __shared__ __align__(16) float lds[N];
    const int t = threadIdx.x;  // 0..127 (2 waves)
    const size_t rowoff = (size_t)blockIdx.x * N;
    const float* __restrict__ xr = x + rowoff;
    float* __restrict__ yr = out + rowoff;

    float v[32];

    // ---- Load: thread t owns e = (t<<5) | m, m = 0..31. 8x b128,
    // thread-contiguous 128 B; the wave's 8 insts cover a contiguous 8 KB,
    // every 64-B line fetched exactly once (L1 merges the per-inst splits).
#pragma unroll
    for (int q = 0; q < 8; ++q) {
        const f32x4 d = *reinterpret_cast<const f32x4*>(xr + (t << 5) + 4 * q);
        v[4 * q + 0] = d[0];
        v[4 * q + 1] = d[1];
        v[4 * q + 2] = d[2];
        v[4 * q + 3] = d[3];
    }

    // ---- Phase A1: butterfly bits 0-4 (h = 1..16) in registers.
#pragma unroll
    for (int b = 1; b < 32; b <<= 1) {
#pragma unroll
        for (int m = 0; m < 32; ++m) {
            if ((m & b) == 0) {
                const float a = v[m], c = v[m | b];
                v[m]     = a + c;
                v[m | b] = a - c;
            }
        }
    }

    // ---- Phase A2: bits 5-6 are lane bits 0-1. Butterfly across lanes via
    // shuffle: partner p = v@(lane^k); new v = s*v + p where s = +1 on the
    // low lane of the pair (a+c), -1 on the high lane (a-c).
    {
        const float s0 = (t & 1) ? -1.0f : 1.0f;
#pragma unroll
        for (int m = 0; m < 32; ++m) {
            const float p = __shfl_xor(v[m], 1, 64);
            v[m] = fmaf(s0, v[m], p);
        }
        const float s1 = (t & 2) ? -1.0f : 1.0f;
#pragma unroll
        for (int m = 0; m < 32; ++m) {
            const float p = __shfl_xor(v[m], 2, 64);
            v[m] = fmaf(s1, v[m], p);
        }
    }

    // ---- LDS transpose write: quad m = 4q..4q+3 of element (t<<5)|m at
    // word (t<<5) | (4q ^ ((t&7)<<2)). XOR only touches bits 2-4 -> 16 B
    // alignment preserved.
    {
        const int T = (t & 7) << 2;
        const int wbase = t << 5;
#pragma unroll
        for (int q = 0; q < 8; ++q) {
            f32x4 d;
            d[0] = v[4 * q + 0];
            d[1] = v[4 * q + 1];
            d[2] = v[4 * q + 2];
            d[3] = v[4 * q + 3];
            *reinterpret_cast<f32x4*>(&lds[wbase | ((4 * q) ^ T)]) = d;
        }
    }
    __syncthreads();

    // ---- LDS read: thread t now owns e = (m2<<7) | t, m2 = 0..31
    // (bits 7-11 local). Address folds to 2 address VGPRs (m2 parity flips
    // bit 4) + imm offsets m2<<7 words.
#pragma unroll
    for (int m2 = 0; m2 < 32; ++m2) {
        const int e = (m2 << 7) | t;
        v[m2] = lds[e ^ (((e >> 5) & 7) << 2)];
    }

    // ---- Phase B: butterfly bits 7-11 (h = 128..2048) on local index m2.
#pragma unroll
    for (int b = 1; b < 32; b <<= 1) {
#pragma unroll
        for (int m = 0; m < 32; ++m) {
            if ((m & b) == 0) {
                const float a = v[m], c = v[m | b];
                v[m]     = a + c;
                v[m | b] = a - c;
            }
        }
    }

    // ---- Store: out[(m2<<7) | t] — each wave-inst writes a contiguous
    // 256 B (4 full lines). Nontemporal: output is never re-read; keeps
    // L3 free for the input.
#pragma unroll
    for (int m2 = 0; m2 < 32; ++m2) {
        __builtin_nontemporal_store(v[m2], yr + (m2 << 7) + t);
    }
}

extern "C" void kernel_launch(void* const* d_in, const int* in_sizes, int n_in,
                              void* d_out, int out_size, void* d_ws, size_t ws_size,
                              hipStream_t stream) {
    (void)n_in; (void)d_ws; (void)ws_size; (void)out_size; (void)in_sizes;
    const float* x = (const float*)d_in[0];  // [8192, 4096] fp32
    float* out = (float*)d_out;              // [8192, 4096] fp32
    fwht4096_kernel<<<ROWS, 128, 0, stream>>>(x, out);
}

// Round 6
// 254.855 us; speedup vs baseline: 1.0016x; 1.0010x over previous
//
#include <hip/hip_runtime.h>

// out = x @ H, H = 4096x4096 Sylvester Hadamard (+/-1) -> per-row fast
// Walsh-Hadamard transform, O(N log N). H (d_in[1]) never read.
// Traffic floor ~265 MB -> ~32-43 us at achievable HBM BW.
//
// R8 vs R7: R7 doubled occupancy (18->38%) with ZERO duration change
// (84->81 us, hbm 2.47 TB/s) -> falsifies latency-bound theory; kernel is
// throughput-bound on the memory path. fillBuffer does 6.7 TB/s on the same
// machine. Two pattern defects fixed here, everything else kept:
//  (1) loads were lane-stride-128B dwordx4 (64 distinct lines per wave-inst,
//      4x line-touch amplification in TA/L1). Now: thread owns
//      e = 512q + 4t + j -> each load inst covers a CONTIGUOUS 1 KiB.
//  (2) stores were nontemporal (suspected L2 write-combine bypass,
//      ~1.7 TB/s ceiling ~= 131 MB / 77 us). Now: plain cached stores,
//      each wave-inst writes 4 full 64-B lines.
// Bit split: regs {0,1,9,10,11} -> shfl {2,3} -> LDS transpose ->
// regs {4,5,6,7,8}. One barrier, 16 KB LDS, 128 thr/row.

constexpr int N = 4096;
constexpr int ROWS = 8192;

typedef float f32x4 __attribute__((ext_vector_type(4)));

// LDS swizzle A(e) = e ^ ((e>>9)&1)<<4 ^ ((e>>10)&1)<<2.
//  Write side (b128, fixed q, lanes t): A = 512q + (4t ^ ((q&1)<<4) ^
//    (((q>>1)&1)<<2)); 16B-group index = (t&7) ^ const -> 8 lanes per
//    4-bank group, uniformly balanced = structural minimum for b128
//    (same class as R7's measured-0-conflict writes).
//  Read side (b32, fixed m, lanes l): bank = [(l&15) ^ ((l>>5)&1)<<2]
//    | [((m&1) ^ ((l>>4)&1)) << 4]; the 4 lanes sharing (l&15) map to 4
//    DISTINCT banks; each bank gets exactly 2 lanes -> free on gfx950.
__device__ __forceinline__ int swz(int e) {
    return e ^ (((e >> 9) & 1) << 4) ^ (((e >> 10) & 1) << 2);
}

__global__ __launch_bounds__(128) void fwht4096_kernel(const float* __restrict__ x,
                                                       float* __restrict__ out) {
    __shared__ __align__(16) float lds[N];
    const int t = threadIdx.x;  // 0..127 (2 waves)
    const size_t rowoff = (size_t)blockIdx.x * N;
    const float* __restrict__ xr = x + rowoff;
    float* __restrict__ yr = out + rowoff;

    float v[8][4];

    // ---- Load: e = 512q + 4t + j. Per wave-inst (fixed q): lane i reads
    // 16 B at base + 16*i -> one contiguous 1 KiB segment (ideal pattern).
#pragma unroll
    for (int q = 0; q < 8; ++q) {
        const f32x4 d = *reinterpret_cast<const f32x4*>(xr + 512 * q + 4 * t);
        v[q][0] = d[0]; v[q][1] = d[1]; v[q][2] = d[2]; v[q][3] = d[3];
    }

    // ---- Butterfly bits 0-1 (j): h = 1, 2.
#pragma unroll
    for (int q = 0; q < 8; ++q) {
        const float a0 = v[q][0] + v[q][1];
        const float a1 = v[q][0] - v[q][1];
        const float a2 = v[q][2] + v[q][3];
        const float a3 = v[q][2] - v[q][3];
        v[q][0] = a0 + a2;
        v[q][1] = a1 + a3;
        v[q][2] = a0 - a2;
        v[q][3] = a1 - a3;
    }
    // ---- Butterfly bits 9-11 (q): h = 512, 1024, 2048.
#pragma unroll
    for (int b = 1; b < 8; b <<= 1) {
#pragma unroll
        for (int q = 0; q < 8; ++q) {
            if ((q & b) == 0) {
#pragma unroll
                for (int j = 0; j < 4; ++j) {
                    const float a = v[q][j], c = v[q | b][j];
                    v[q][j]     = a + c;
                    v[q | b][j] = a - c;
                }
            }
        }
    }
    // ---- Butterfly bits 2-3 (= lane bits 0-1) via shfl_xor + sign-fma
    // (low lane of pair: a+c; high lane: -a+c = a-c with roles swapped).
    {
        const float s0 = (t & 1) ? -1.0f : 1.0f;
#pragma unroll
        for (int q = 0; q < 8; ++q)
#pragma unroll
            for (int j = 0; j < 4; ++j) {
                const float p = __shfl_xor(v[q][j], 1, 64);
                v[q][j] = fmaf(s0, v[q][j], p);
            }
        const float s1 = (t & 2) ? -1.0f : 1.0f;
#pragma unroll
        for (int q = 0; q < 8; ++q)
#pragma unroll
            for (int j = 0; j < 4; ++j) {
                const float p = __shfl_xor(v[q][j], 2, 64);
                v[q][j] = fmaf(s1, v[q][j], p);
            }
    }

    // ---- LDS transpose write: quad j=0..3 of e0 = 512q + 4t at A(e0)
    // (XOR terms constant over the quad; 16-B alignment preserved).
#pragma unroll
    for (int q = 0; q < 8; ++q) {
        f32x4 d;
        d[0] = v[q][0]; d[1] = v[q][1]; d[2] = v[q][2]; d[3] = v[q][3];
        *reinterpret_cast<f32x4*>(&lds[swz(512 * q + 4 * t)]) = d;
    }
    __syncthreads();

    // ---- LDS read: thread owns e = (t&15) | (m<<4) | ((t>>4)<<9),
    // m = 0..31 (bits 4-8 local). 2 lanes/bank by construction.
    float w[32];
    const int ebase = (t & 15) | ((t >> 4) << 9);
#pragma unroll
    for (int m = 0; m < 32; ++m) {
        w[m] = lds[swz(ebase | (m << 4))];
    }

    // ---- Butterfly bits 4-8: h = 16, 32, 64, 128, 256.
#pragma unroll
    for (int b = 1; b < 32; b <<= 1) {
#pragma unroll
        for (int m = 0; m < 32; ++m) {
            if ((m & b) == 0) {
                const float a = w[m], c = w[m | b];
                w[m]     = a + c;
                w[m | b] = a - c;
            }
        }
    }

    // ---- Store: plain cached scalar stores. Per wave-inst (fixed m):
    // lanes cover bits 0-3 (contiguous 64 B) x bits 9-10 -> 4 FULL 64-B
    // lines, full-rate L2 write-combining (fillBuffer path).
#pragma unroll
    for (int m = 0; m < 32; ++m) {
        yr[ebase | (m << 4)] = w[m];
    }
}

extern "C" void kernel_launch(void* const* d_in, const int* in_sizes, int n_in,
                              void* d_out, int out_size, void* d_ws, size_t ws_size,
                              hipStream_t stream) {
    (void)n_in; (void)d_ws; (void)ws_size; (void)out_size; (void)in_sizes;
    const float* x = (const float*)d_in[0];  // [8192, 4096] fp32
    float* out = (float*)d_out;              // [8192, 4096] fp32
    fwht4096_kernel<<<ROWS, 128, 0, stream>>>(x, out);
}